// Round 10
// baseline (138.812 us; speedup 1.0000x reference)
//
#include <hip/hip_runtime.h>
#include <hip/hip_bf16.h>

#define NB 2
#define ND 256
#define NE 2048
#define NH 4
#define MAXP 8

typedef __attribute__((ext_vector_type(8))) short bf16x8;
typedef __attribute__((ext_vector_type(4))) float f32x4;

static __device__ __forceinline__ short f2b(float f) {
    union { __hip_bfloat16 h; short s; } u;
    u.h = __float2bfloat16(f);
    return u.s;
}

static __device__ __forceinline__ float b2f(short s) {
    union { unsigned int u; float f; } u;
    u.u = ((unsigned int)(unsigned short)s) << 16;
    return u.f;
}

static __device__ __forceinline__ f32x4 mfma16(bf16x8 a, bf16x8 b, f32x4 c) {
    return __builtin_amdgcn_mfma_f32_16x16x32_bf16(a, b, c, 0, 0, 0);
}

static __device__ __forceinline__ f32x4 mfma8(long long a, long long b, f32x4 c) {
    return __builtin_amdgcn_mfma_f32_16x16x32_fp8_fp8(a, b, c, 0, 0, 0);
}

// ---------------- f32 -> bf16 convert, all 4 weight matrices ----------------
__global__ __launch_bounds__(256) void k_cvt_all(const float* __restrict__ w0,
        const float* __restrict__ w1, const float* __restrict__ w2,
        const float* __restrict__ w3, short* __restrict__ o0,
        short* __restrict__ o1, short* __restrict__ o2, short* __restrict__ o3) {
    int which = blockIdx.x >> 6;
    int i = (blockIdx.x & 63) * 256 + threadIdx.x;
    const float* in = which == 0 ? w0 : which == 1 ? w1 : which == 2 ? w2 : w3;
    short* out = which == 0 ? o0 : which == 1 ? o1 : which == 2 ? o2 : o3;
    float scale = which == 0 ? 0.125f : 1.0f;
    f32x4 v = ((const f32x4*)in)[i];
    short4 o;
    o.x = f2b(v[0] * scale); o.y = f2b(v[1] * scale);
    o.z = f2b(v[2] * scale); o.w = f2b(v[3] * scale);
    ((short4*)out)[i] = o;
}

// ---------------- fused transpose + layernorm: x [B,D,E] -> sbf, qnb ----------
__global__ __launch_bounds__(256) void k_prep(const float* __restrict__ x,
        const float* __restrict__ g, const float* __restrict__ bb,
        short* __restrict__ sbf, short* __restrict__ qnb) {
    __shared__ float tileT[32][257];
    int b = blockIdx.y;
    int e0 = blockIdx.x * 32;
    int t = threadIdx.x;
    int tx = t & 31, ty = t >> 5; // 32 x 8
    #pragma unroll
    for (int d0 = 0; d0 < 256; d0 += 32) {
        #pragma unroll
        for (int r = 0; r < 4; r++) {
            int dd = d0 + ty + r * 8;
            tileT[tx][dd] = x[((size_t)b * ND + dd) * NE + e0 + tx];
        }
    }
    __syncthreads();
    int wave = t >> 6, lane = t & 63;
    #pragma unroll 1
    for (int rr = 0; rr < 8; rr++) {
        int e = wave * 8 + rr;
        float v0 = tileT[e][lane], v1 = tileT[e][lane + 64];
        float v2 = tileT[e][lane + 128], v3 = tileT[e][lane + 192];
        float sum = (v0 + v1) + (v2 + v3);
        #pragma unroll
        for (int off = 32; off; off >>= 1) sum += __shfl_xor(sum, off);
        float mean = sum * (1.0f / ND);
        float d0 = v0 - mean, d1 = v1 - mean, d2 = v2 - mean, d3 = v3 - mean;
        float sq = (d0 * d0 + d1 * d1) + (d2 * d2 + d3 * d3);
        #pragma unroll
        for (int off = 32; off; off >>= 1) sq += __shfl_xor(sq, off);
        float inv = rsqrtf(sq * (1.0f / ND) + 1e-6f);
        size_t base = ((size_t)b * NE + e0 + e) * ND;
        sbf[base + lane]       = f2b(v0);
        sbf[base + lane + 64]  = f2b(v1);
        sbf[base + lane + 128] = f2b(v2);
        sbf[base + lane + 192] = f2b(v3);
        qnb[base + lane]       = f2b(d0 * inv * g[lane]       + bb[lane]);
        qnb[base + lane + 64]  = f2b(d1 * inv * g[lane + 64]  + bb[lane + 64]);
        qnb[base + lane + 128] = f2b(d2 * inv * g[lane + 128] + bb[lane + 128]);
        qnb[base + lane + 192] = f2b(d3 * inv * g[lane + 192] + bb[lane + 192]);
    }
}

// ---------------- merged QKV MFMA GEMM (+ qdr table in z=0 epilogue) ----------
__global__ __launch_bounds__(256) void k_gemm_qkv(const short* __restrict__ qnb,
        const short* __restrict__ sbf, const short* __restrict__ wq,
        const short* __restrict__ wk, const short* __restrict__ wv,
        const float* __restrict__ w_rpr, short* __restrict__ qbf,
        short* __restrict__ kbf, unsigned char* __restrict__ vtb8,
        float* __restrict__ qdrT) {
    int z = blockIdx.z;
    const short* A = z == 0 ? qnb : sbf;
    const short* W = z == 0 ? wq : z == 1 ? wk : wv;
    int t = threadIdx.x;
    int wv_ = t >> 6, lane = t & 63;
    int l16 = lane & 15, g = lane >> 4, lk = g * 8;
    int m0 = blockIdx.x * 64, n0 = blockIdx.y * 64;
    int mw = m0 + wv_ * 16;
    const short* Ab = A + (size_t)(mw + l16) * 256 + lk;
    const short* Wb = W + (size_t)(n0 + l16) * 256 + lk;
    __shared__ float wr[9][64];
    if (z == 0) {
        for (int i = t; i < 576; i += 256) wr[i >> 6][i & 63] = w_rpr[i];
    }
    f32x4 acc[4];
    f32x4 z4 = {0.f, 0.f, 0.f, 0.f};
    #pragma unroll
    for (int c = 0; c < 4; c++) acc[c] = z4;
    #pragma unroll
    for (int kk = 0; kk < 8; kk++) {
        bf16x8 av = *(const bf16x8*)(Ab + kk * 32);
        #pragma unroll
        for (int c = 0; c < 4; c++) {
            bf16x8 bv = *(const bf16x8*)(Wb + (size_t)c * 16 * 256 + kk * 32);
            acc[c] = mfma16(av, bv, acc[c]);
        }
    }
    if (z < 2) {
        short* out = z == 0 ? qbf : kbf;
        #pragma unroll
        for (int c = 0; c < 4; c++)
            #pragma unroll
            for (int r = 0; r < 4; r++)
                out[(size_t)(mw + g * 4 + r) * 256 + n0 + c * 16 + l16] = f2b(acc[c][r]);
        if (z == 0) {
            __syncthreads();
            int h = blockIdx.y;
            #pragma unroll
            for (int r = 0; r < 4; r++) {
                size_t row = mw + g * 4 + r;
                size_t base = (row * NH + h) * 10;
                #pragma unroll
                for (int p = 0; p < 9; p++) {
                    float v = acc[0][r] * wr[p][l16] + acc[1][r] * wr[p][16 + l16]
                            + acc[2][r] * wr[p][32 + l16] + acc[3][r] * wr[p][48 + l16];
                    v += __shfl_xor(v, 1); v += __shfl_xor(v, 2);
                    v += __shfl_xor(v, 4); v += __shfl_xor(v, 8);
                    if (l16 == 0) qdrT[base + p] = __expf(v);
                }
                if (l16 == 0) qdrT[base + 9] = 0.f;
            }
        }
    } else {
        __shared__ unsigned char vt[64][72];
        #pragma unroll
        for (int c = 0; c < 4; c++) {
            #pragma unroll
            for (int r = 0; r < 4; r++) {
                unsigned u = __builtin_amdgcn_cvt_pk_fp8_f32(acc[c][r], 0.f, 0, false);
                vt[c * 16 + l16][wv_ * 16 + g * 4 + r] = (unsigned char)(u & 0xFF);
            }
        }
        __syncthreads();
        int b = m0 >> 11, e0 = m0 & (NE - 1);
        int bh = b * NH + blockIdx.y;
        int dl = t >> 2, ec = (t & 3) * 16;
        long long v0 = *(const long long*)&vt[dl][ec];
        long long v1 = *(const long long*)&vt[dl][ec + 8];
        size_t base = ((size_t)bh * 64 + dl) * NE + e0 + ec;
        *(long long*)&vtb8[base] = v0;
        *(long long*)&vtb8[base + 8] = v1;
    }
}

// ---------------- single-pass fused attention: P in registers ----------------
// grid (NE/16, NB*NH), block 512 (8 waves). Wave ph owns tiles n0=(ph+8j)*64.
// Swapped mfma(K,Q): lane (l16,g) holds P[q=l16][k=n0+c*16+g*4 .. +3] packed
// fp8 in pu[j][c]. PV A-fragments rebuilt via __shfl (4 shuffles + 2 selects
// per 32-tile). No LDS P, no barrier in the j-loop; normalization applied
// after the rs reduce to both a_out and oatb.
__global__ __launch_bounds__(512, 4) void k_attn(
        const short* __restrict__ qbf, const short* __restrict__ kbf,
        const int* __restrict__ dist, const float* __restrict__ qdrT,
        const unsigned char* __restrict__ vtb8, float* __restrict__ a_out,
        short* __restrict__ oatb) {
    __shared__ float qdr_lds[16][10];
    __shared__ float comb[8][16];
    __shared__ float inv_lds[16];
    __shared__ float pvcomb[7][16][64];   // 28.7 KB

    int t = threadIdx.x;
    int ph = t >> 6, lane = t & 63;
    int l16 = lane & 15, g = lane >> 4, lk = g * 8;
    int bh = blockIdx.y, b = bh >> 2, h = bh & 3;
    int m0 = blockIdx.x * 16;

    if (t < 160) {
        int row = t / 10, p = t - row * 10;
        qdr_lds[row][p] = qdrT[((size_t)(b * NE + m0 + row) * NH + h) * 10 + p];
    }
    __syncthreads();

    const short* Abase = qbf + (size_t)(b * NE + m0 + l16) * 256 + h * 64 + lk;
    bf16x8 aq0 = *(const bf16x8*)(Abase);
    bf16x8 aq1 = *(const bf16x8*)(Abase + 32);

    const short* Kb = kbf + (size_t)(b * NE + l16) * 256 + h * 64 + lk;
    const int* distq = dist + ((size_t)(b * NE + m0 + l16)) * NE;
    const unsigned char* Vb0 = vtb8 + ((size_t)bh * 64 + l16) * NE;

    float rs = 0.f;
    unsigned pu[4][4];
    f32x4 accp[4];
    {
        f32x4 z4 = {0.f, 0.f, 0.f, 0.f};
        #pragma unroll
        for (int c = 0; c < 4; c++) accp[c] = z4;
    }

    int src_lo = l16 + 16 * (2 * (g & 1));
    int src_hi = src_lo + 16;

    #pragma unroll
    for (int j = 0; j < 4; j++) {
        int n0 = (ph + 8 * j) * 64;
        // ---- QK^T + exp + pack (swapped operands) ----
        #pragma unroll
        for (int c = 0; c < 4; c++) {
            const short* Bb = Kb + (size_t)(n0 + c * 16) * 256;
            bf16x8 kv0 = *(const bf16x8*)(Bb);
            bf16x8 kv1 = *(const bf16x8*)(Bb + 32);
            f32x4 acc = {0.f, 0.f, 0.f, 0.f};
            acc = mfma16(kv0, aq0, acc);
            acc = mfma16(kv1, aq1, acc);
            int kbase = n0 + c * 16 + g * 4;
            int4 dd = *(const int4*)&distq[kbase];
            float e0 = __expf(acc[0]) * qdr_lds[l16][dd.x < 9 ? dd.x : 9];
            float e1 = __expf(acc[1]) * qdr_lds[l16][dd.y < 9 ? dd.y : 9];
            float e2 = __expf(acc[2]) * qdr_lds[l16][dd.z < 9 ? dd.z : 9];
            float e3 = __expf(acc[3]) * qdr_lds[l16][dd.w < 9 ? dd.w : 9];
            rs += (e0 + e1) + (e2 + e3);
            unsigned u = __builtin_amdgcn_cvt_pk_fp8_f32(e0, e1, 0, false);
            u = (unsigned)__builtin_amdgcn_cvt_pk_fp8_f32(e2, e3, (int)u, true);
            pu[j][c] = u;
        }
        // ---- PV immediately (unnormalized), A-frag via shuffles ----
        #pragma unroll
        for (int tt = 0; tt < 2; tt++) {
            int aa0 = __shfl((int)pu[j][2 * tt],     src_lo);
            int bb0 = __shfl((int)pu[j][2 * tt + 1], src_lo);
            int aa1 = __shfl((int)pu[j][2 * tt],     src_hi);
            int bb1 = __shfl((int)pu[j][2 * tt + 1], src_hi);
            unsigned lo = (g < 2) ? (unsigned)aa0 : (unsigned)bb0;
            unsigned hi = (g < 2) ? (unsigned)aa1 : (unsigned)bb1;
            long long pa = (long long)(((unsigned long long)hi << 32) | lo);
            #pragma unroll
            for (int c = 0; c < 4; c++) {
                long long vb = *(const long long*)(Vb0 + (size_t)c * 16 * NE + n0 + tt * 32 + lk);
                accp[c] = mfma8(pa, vb, accp[c]);
            }
        }
    }

    // ---- row-sum reduce across the wave and the 8 waves ----
    rs += __shfl_xor(rs, 16);
    rs += __shfl_xor(rs, 32);
    if (lane < 16) comb[ph][l16] = rs;
    __syncthreads();
    if (t < 16) {
        float s = 0.f;
        #pragma unroll
        for (int w = 0; w < 8; w++) s += comb[w][t];
        inv_lds[t] = 1.0f / s;
    }
    __syncthreads();

    // ---- a_out: normalized f32 from retained registers ----
    {
        float iv = inv_lds[l16];
        size_t rowbase = ((size_t)bh * NE + m0 + l16) * NE;
        #pragma unroll
        for (int j = 0; j < 4; j++) {
            int n0 = (ph + 8 * j) * 64;
            #pragma unroll
            for (int c = 0; c < 4; c++) {
                unsigned u = pu[j][c];
                f32x4 o;
                o[0] = __builtin_amdgcn_cvt_f32_fp8((int)u, 0) * iv;
                o[1] = __builtin_amdgcn_cvt_f32_fp8((int)u, 1) * iv;
                o[2] = __builtin_amdgcn_cvt_f32_fp8((int)u, 2) * iv;
                o[3] = __builtin_amdgcn_cvt_f32_fp8((int)u, 3) * iv;
                *(f32x4*)&a_out[rowbase + n0 + c * 16 + g * 4] = o;
            }
        }
    }

    // ---- combine PV partials across 8 waves, write oatb ----
    if (ph > 0) {
        #pragma unroll
        for (int c = 0; c < 4; c++)
            #pragma unroll
            for (int r = 0; r < 4; r++)
                pvcomb[ph - 1][g * 4 + r][c * 16 + l16] = accp[c][r];
    }
    __syncthreads();
    if (ph == 0) {
        #pragma unroll
        for (int c = 0; c < 4; c++) {
            #pragma unroll
            for (int r = 0; r < 4; r++) {
                float v = accp[c][r];
                #pragma unroll
                for (int w = 0; w < 7; w++) v += pvcomb[w][g * 4 + r][c * 16 + l16];
                v *= inv_lds[g * 4 + r];
                oatb[(size_t)(b * NE + m0 + g * 4 + r) * 256 + h * 64 + c * 16 + l16] = f2b(v);
            }
        }
    }
}

// ---------------- fc GEMM + residual from x + transposed store ----------------
__global__ __launch_bounds__(256) void k_gemm_fc(const short* __restrict__ A,
        const short* __restrict__ W, const float* __restrict__ x,
        float* __restrict__ xout) {
    int t = threadIdx.x;
    int wv_ = t >> 6, lane = t & 63;
    int l16 = lane & 15, g = lane >> 4, lk = g * 8;
    int m0 = blockIdx.x * 64, n0 = blockIdx.y * 64;
    int mw = m0 + wv_ * 16;
    const short* Ab = A + (size_t)(mw + l16) * 256 + lk;
    const short* Wb = W + (size_t)(n0 + l16) * 256 + lk;
    f32x4 acc[4];
    f32x4 z4 = {0.f, 0.f, 0.f, 0.f};
    #pragma unroll
    for (int c = 0; c < 4; c++) acc[c] = z4;
    #pragma unroll
    for (int kk = 0; kk < 8; kk++) {
        bf16x8 av = *(const bf16x8*)(Ab + kk * 32);
        #pragma unroll
        for (int c = 0; c < 4; c++) {
            bf16x8 bv = *(const bf16x8*)(Wb + (size_t)c * 16 * 256 + kk * 32);
            acc[c] = mfma16(av, bv, acc[c]);
        }
    }
    __shared__ float tl[64][68];
    #pragma unroll
    for (int c = 0; c < 4; c++)
        #pragma unroll
        for (int r = 0; r < 4; r++)
            tl[c * 16 + l16][wv_ * 16 + g * 4 + r] = acc[c][r];
    __syncthreads();
    int b = m0 >> 11, e0 = m0 & (NE - 1);
    int dl = t >> 2, ec = (t & 3) * 16;
    #pragma unroll
    for (int i = 0; i < 4; i++) {
        size_t idx = ((size_t)b * ND + n0 + dl) * NE + e0 + ec + i * 4;
        f32x4 xv = *(const f32x4*)&x[idx];
        f32x4 v = *(f32x4*)&tl[dl][ec + i * 4];
        v[0] += xv[0]; v[1] += xv[1]; v[2] += xv[2]; v[3] += xv[3];
        *(f32x4*)&xout[idx] = v;
    }
}

extern "C" void kernel_launch(void* const* d_in, const int* in_sizes, int n_in,
                              void* d_out, int out_size, void* d_ws, size_t ws_size,
                              hipStream_t stream) {
    const float* x    = (const float*)d_in[0];
    const int*   dist = (const int*)d_in[1];
    const float* w_qs = (const float*)d_in[2];
    const float* w_ks = (const float*)d_in[3];
    const float* w_vs = (const float*)d_in[4];
    const float* w_fc = (const float*)d_in[5];
    const float* w_rpr= (const float*)d_in[6];
    const float* ln_g = (const float*)d_in[7];
    const float* ln_b = (const float*)d_in[8];

    char* ws = (char*)d_ws;
    short* sbf  = (short*)(ws);                    // 2 MB
    short* qnb  = (short*)(ws + (2u  << 20));      // 2 MB
    short* qbf  = (short*)(ws + (4u  << 20));      // 2 MB
    short* kbf  = (short*)(ws + (6u  << 20));      // 2 MB
    unsigned char* vtb8 = (unsigned char*)(ws + (8u << 20));  // 1 MB
    short* oatb = (short*)(ws + (10u << 20));      // 2 MB
    float* qdrT = (float*)(ws + (12u << 20));      // 640 KB
    short* wqsb = (short*)(ws + (13u << 20));
    short* wksb = (short*)(ws + (13u << 20) + 131072);
    short* wvsb = (short*)(ws + (13u << 20) + 262144);
    short* wfcb = (short*)(ws + (13u << 20) + 393216);

    float* xout  = (float*)d_out;
    float* a_out = xout + (size_t)NB * ND * NE;

    k_cvt_all<<<dim3(256), dim3(256), 0, stream>>>(w_qs, w_ks, w_vs, w_fc,
                                                   wqsb, wksb, wvsb, wfcb);
    k_prep<<<dim3(NE / 32, NB), dim3(256), 0, stream>>>(x, ln_g, ln_b, sbf, qnb);
    k_gemm_qkv<<<dim3(64, 4, 3), dim3(256), 0, stream>>>(qnb, sbf, wqsb, wksb, wvsb,
                                                         w_rpr, qbf, kbf, vtb8, qdrT);
    k_attn<<<dim3(NE / 16, NB * NH), dim3(512), 0, stream>>>(qbf, kbf, dist, qdrT,
                                                             vtb8, a_out, oatb);
    k_gemm_fc<<<dim3(64, 4), dim3(256), 0, stream>>>(oatb, wfcb, x, xout);
}

// Round 12
// 129.375 us; speedup vs baseline: 1.0729x; 1.0729x over previous
//
#include <hip/hip_runtime.h>
#include <hip/hip_bf16.h>

#define NB 2
#define ND 256
#define NE 2048
#define NH 4
#define MAXP 8
#define PSTR8 2064   // LDS P row stride (bytes)

typedef __attribute__((ext_vector_type(8))) short bf16x8;
typedef __attribute__((ext_vector_type(4))) float f32x4;

static __device__ __forceinline__ short f2b(float f) {
    union { __hip_bfloat16 h; short s; } u;
    u.h = __float2bfloat16(f);
    return u.s;
}

static __device__ __forceinline__ float b2f(short s) {
    union { unsigned int u; float f; } u;
    u.u = ((unsigned int)(unsigned short)s) << 16;
    return u.f;
}

static __device__ __forceinline__ f32x4 mfma16(bf16x8 a, bf16x8 b, f32x4 c) {
    return __builtin_amdgcn_mfma_f32_16x16x32_bf16(a, b, c, 0, 0, 0);
}

static __device__ __forceinline__ f32x4 mfma8(long long a, long long b, f32x4 c) {
    return __builtin_amdgcn_mfma_f32_16x16x32_fp8_fp8(a, b, c, 0, 0, 0);
}

static __device__ __forceinline__ unsigned char f2fp8(float f) {
    return (unsigned char)(__builtin_amdgcn_cvt_pk_fp8_f32(f, 0.f, 0, false) & 0xFF);
}

// ---------------- f32 -> bf16 convert, all 4 weight matrices (no scaling) ----
__global__ __launch_bounds__(256) void k_cvt_all(const float* __restrict__ w0,
        const float* __restrict__ w1, const float* __restrict__ w2,
        const float* __restrict__ w3, short* __restrict__ o0,
        short* __restrict__ o1, short* __restrict__ o2, short* __restrict__ o3) {
    int which = blockIdx.x >> 6;
    int i = (blockIdx.x & 63) * 256 + threadIdx.x;
    const float* in = which == 0 ? w0 : which == 1 ? w1 : which == 2 ? w2 : w3;
    short* out = which == 0 ? o0 : which == 1 ? o1 : which == 2 ? o2 : o3;
    f32x4 v = ((const f32x4*)in)[i];
    short4 o;
    o.x = f2b(v[0]); o.y = f2b(v[1]); o.z = f2b(v[2]); o.w = f2b(v[3]);
    ((short4*)out)[i] = o;
}

// ---------------- dist int32 -> d8 uint8 = min(dist, 9) ----------------
__global__ __launch_bounds__(256) void k_d8(const int* __restrict__ dist,
        unsigned char* __restrict__ d8) {
    int i = blockIdx.x * 256 + threadIdx.x;   // grid covers n/4
    int4 v = ((const int4*)dist)[i];
    uchar4 o;
    o.x = (unsigned char)(v.x < 9 ? v.x : 9);
    o.y = (unsigned char)(v.y < 9 ? v.y : 9);
    o.z = (unsigned char)(v.z < 9 ? v.z : 9);
    o.w = (unsigned char)(v.w < 9 ? v.w : 9);
    ((uchar4*)d8)[i] = o;
}

// ---------------- fused transpose + layernorm: x [B,D,E] -> sbf, qnb ----------
__global__ __launch_bounds__(256) void k_prep(const float* __restrict__ x,
        const float* __restrict__ g, const float* __restrict__ bb,
        short* __restrict__ sbf, short* __restrict__ qnb) {
    __shared__ float tileT[32][257];
    int b = blockIdx.y;
    int e0 = blockIdx.x * 32;
    int t = threadIdx.x;
    int tx = t & 31, ty = t >> 5; // 32 x 8
    #pragma unroll
    for (int d0 = 0; d0 < 256; d0 += 32) {
        #pragma unroll
        for (int r = 0; r < 4; r++) {
            int dd = d0 + ty + r * 8;
            tileT[tx][dd] = x[((size_t)b * ND + dd) * NE + e0 + tx];
        }
    }
    __syncthreads();
    int wave = t >> 6, lane = t & 63;
    #pragma unroll 1
    for (int rr = 0; rr < 8; rr++) {
        int e = wave * 8 + rr;
        float v0 = tileT[e][lane], v1 = tileT[e][lane + 64];
        float v2 = tileT[e][lane + 128], v3 = tileT[e][lane + 192];
        float sum = (v0 + v1) + (v2 + v3);
        #pragma unroll
        for (int off = 32; off; off >>= 1) sum += __shfl_xor(sum, off);
        float mean = sum * (1.0f / ND);
        float d0 = v0 - mean, d1 = v1 - mean, d2 = v2 - mean, d3 = v3 - mean;
        float sq = (d0 * d0 + d1 * d1) + (d2 * d2 + d3 * d3);
        #pragma unroll
        for (int off = 32; off; off >>= 1) sq += __shfl_xor(sq, off);
        float inv = rsqrtf(sq * (1.0f / ND) + 1e-6f);
        size_t base = ((size_t)b * NE + e0 + e) * ND;
        sbf[base + lane]       = f2b(v0);
        sbf[base + lane + 64]  = f2b(v1);
        sbf[base + lane + 128] = f2b(v2);
        sbf[base + lane + 192] = f2b(v3);
        qnb[base + lane]       = f2b(d0 * inv * g[lane]       + bb[lane]);
        qnb[base + lane + 64]  = f2b(d1 * inv * g[lane + 64]  + bb[lane + 64]);
        qnb[base + lane + 128] = f2b(d2 * inv * g[lane + 128] + bb[lane + 128]);
        qnb[base + lane + 192] = f2b(d3 * inv * g[lane + 192] + bb[lane + 192]);
    }
}

// ---------------- merged QKV MFMA GEMM ----------------
// grid (64, 4, 3): z=0 q->qf8 fp8 + qdrT8; z=1 k->kf8 fp8; z=2 v->vtb8 fp8 T
// q,k stored UNSCALED fp8 (1/8 temp folded into exp args downstream).
__global__ __launch_bounds__(256) void k_gemm_qkv(const short* __restrict__ qnb,
        const short* __restrict__ sbf, const short* __restrict__ wq,
        const short* __restrict__ wk, const short* __restrict__ wv,
        const float* __restrict__ w_rpr, unsigned char* __restrict__ qf8,
        unsigned char* __restrict__ kf8, unsigned char* __restrict__ vtb8,
        uint4* __restrict__ qdrT8) {
    int z = blockIdx.z;
    const short* A = z == 0 ? qnb : sbf;
    const short* W = z == 0 ? wq : z == 1 ? wk : wv;
    int t = threadIdx.x;
    int wv_ = t >> 6, lane = t & 63;
    int l16 = lane & 15, g = lane >> 4, lk = g * 8;
    int m0 = blockIdx.x * 64, n0 = blockIdx.y * 64;
    int mw = m0 + wv_ * 16;
    const short* Ab = A + (size_t)(mw + l16) * 256 + lk;
    const short* Wb = W + (size_t)(n0 + l16) * 256 + lk;
    __shared__ float wr[9][64];
    if (z == 0) {
        for (int i = t; i < 576; i += 256) wr[i >> 6][i & 63] = w_rpr[i];
    }
    f32x4 acc[4];
    f32x4 z4 = {0.f, 0.f, 0.f, 0.f};
    #pragma unroll
    for (int c = 0; c < 4; c++) acc[c] = z4;
    #pragma unroll
    for (int kk = 0; kk < 8; kk++) {
        bf16x8 av = *(const bf16x8*)(Ab + kk * 32);
        #pragma unroll
        for (int c = 0; c < 4; c++) {
            bf16x8 bv = *(const bf16x8*)(Wb + (size_t)c * 16 * 256 + kk * 32);
            acc[c] = mfma16(av, bv, acc[c]);
        }
    }
    if (z < 2) {
        // qdr exp-table (q only), computed from registers
        if (z == 0) {
            __syncthreads();   // wr ready
            int h = blockIdx.y;
            #pragma unroll
            for (int r = 0; r < 4; r++) {
                float tv[9];
                #pragma unroll
                for (int p = 0; p < 9; p++) {
                    float v = acc[0][r] * wr[p][l16] + acc[1][r] * wr[p][16 + l16]
                            + acc[2][r] * wr[p][32 + l16] + acc[3][r] * wr[p][48 + l16];
                    v += __shfl_xor(v, 1); v += __shfl_xor(v, 2);
                    v += __shfl_xor(v, 4); v += __shfl_xor(v, 8);
                    tv[p] = __expf(v * 0.125f);
                }
                if (l16 == 0) {
                    unsigned lo = __builtin_amdgcn_cvt_pk_fp8_f32(tv[0], tv[1], 0, false);
                    lo = (unsigned)__builtin_amdgcn_cvt_pk_fp8_f32(tv[2], tv[3], (int)lo, true);
                    unsigned hi = __builtin_amdgcn_cvt_pk_fp8_f32(tv[4], tv[5], 0, false);
                    hi = (unsigned)__builtin_amdgcn_cvt_pk_fp8_f32(tv[6], tv[7], (int)hi, true);
                    uint4 o;
                    o.x = lo; o.y = hi;
                    o.z = (unsigned)__float_as_int(tv[8]);
                    o.w = 0u;
                    qdrT8[(size_t)(mw + g * 4 + r) * NH + h] = o;
                }
            }
        }
        // fp8 row-major store via LDS tile
        __shared__ unsigned char ft[64][80];
        #pragma unroll
        for (int c = 0; c < 4; c++)
            #pragma unroll
            for (int r = 0; r < 4; r++)
                ft[wv_ * 16 + g * 4 + r][c * 16 + l16] = f2fp8(acc[c][r]);
        __syncthreads();
        unsigned char* out = z == 0 ? qf8 : kf8;
        int row = t >> 2, colq = (t & 3) * 16;
        uint4 v = *(const uint4*)&ft[row][colq];
        *(uint4*)&out[(size_t)(m0 + row) * 256 + n0 + colq] = v;
    } else {
        __shared__ unsigned char vt[64][72];
        #pragma unroll
        for (int c = 0; c < 4; c++) {
            #pragma unroll
            for (int r = 0; r < 4; r++)
                vt[c * 16 + l16][wv_ * 16 + g * 4 + r] = f2fp8(acc[c][r]);
        }
        __syncthreads();
        int b = m0 >> 11, e0 = m0 & (NE - 1);
        int bh = b * NH + blockIdx.y;
        int dl = t >> 2, ec = (t & 3) * 16;
        long long v0 = *(const long long*)&vt[dl][ec];
        long long v1 = *(const long long*)&vt[dl][ec + 8];
        size_t base = ((size_t)bh * 64 + dl) * NE + e0 + ec;
        *(long long*)&vtb8[base] = v0;
        *(long long*)&vtb8[base + 8] = v1;
    }
}

// ---------------- fused scores+softmax+PV; all-fp8; register T-LUT ------------
// grid (NE/16, NB*NH), block 512 (8 waves). Wave ph owns tiles n0=(ph+8j)*64.
// Swapped mfma8(K,Q). e = exp(0.125*s) * T[d8] where T bytes live in 2 VGPRs
// selected by v_perm with the d8 word as selector (d8>=8 overridden: 8->T8, 9->0).
__global__ __launch_bounds__(512, 4) void k_attn(
        const unsigned char* __restrict__ qf8, const unsigned char* __restrict__ kf8,
        const unsigned char* __restrict__ d8, const uint4* __restrict__ qdrT8,
        const unsigned char* __restrict__ vtb8, float* __restrict__ a_out,
        short* __restrict__ oatb) {
    __shared__ __align__(16) unsigned char P[16][PSTR8];  // 33.0 KB fp8
    __shared__ float comb[8][16];
    __shared__ float inv_lds[16];

    int t = threadIdx.x;
    int ph = t >> 6, lane = t & 63;
    int l16 = lane & 15, g = lane >> 4;
    int bh = blockIdx.y, b = bh >> 2, h = bh & 3;
    int m0 = blockIdx.x * 16;

    // per-lane T LUT for q-row l16
    uint4 tw = qdrT8[(size_t)(b * NE + m0 + l16) * NH + h];
    unsigned Tlo = tw.x, Thi = tw.y;
    float T8f = __int_as_float((int)tw.z);

    const unsigned char* Qb = qf8 + (size_t)(b * NE + m0 + l16) * 256 + h * 64 + g * 8;
    long long aq0 = *(const long long*)(Qb);
    long long aq1 = *(const long long*)(Qb + 32);

    const unsigned char* Kb = kf8 + (size_t)(b * NE + l16) * 256 + h * 64 + g * 8;
    const unsigned char* d8q = d8 + ((size_t)(b * NE + m0 + l16)) * NE;

    float rs = 0.f;

    // ---------------- pass 1: fp8 QK^T -> exp -> fp8 P, row sums --------------
    #pragma unroll 1
    for (int j = 0; j < 4; j++) {
        int n0 = (ph + 8 * j) * 64;
        #pragma unroll
        for (int c = 0; c < 4; c++) {
            const unsigned char* Bb = Kb + (size_t)(n0 + c * 16) * 256;
            long long kv0 = *(const long long*)(Bb);
            long long kv1 = *(const long long*)(Bb + 32);
            f32x4 acc = {0.f, 0.f, 0.f, 0.f};
            acc = mfma8(kv0, aq0, acc);
            acc = mfma8(kv1, aq1, acc);
            int kbase = n0 + c * 16 + g * 4;
            unsigned sel = *(const unsigned*)&d8q[kbase];
            unsigned tpk = __builtin_amdgcn_perm(Thi, Tlo, sel);
            float tf0 = __builtin_amdgcn_cvt_f32_fp8((int)tpk, 0);
            float tf1 = __builtin_amdgcn_cvt_f32_fp8((int)tpk, 1);
            float tf2 = __builtin_amdgcn_cvt_f32_fp8((int)tpk, 2);
            float tf3 = __builtin_amdgcn_cvt_f32_fp8((int)tpk, 3);
            unsigned db0 = sel & 0xFFu;
            unsigned db1 = (sel >> 8) & 0xFFu;
            unsigned db2 = (sel >> 16) & 0xFFu;
            unsigned db3 = (sel >> 24) & 0xFFu;
            tf0 = db0 < 8 ? tf0 : (db0 == 8 ? T8f : 0.f);
            tf1 = db1 < 8 ? tf1 : (db1 == 8 ? T8f : 0.f);
            tf2 = db2 < 8 ? tf2 : (db2 == 8 ? T8f : 0.f);
            tf3 = db3 < 8 ? tf3 : (db3 == 8 ? T8f : 0.f);
            float e0 = __expf(acc[0] * 0.125f) * tf0;
            float e1 = __expf(acc[1] * 0.125f) * tf1;
            float e2 = __expf(acc[2] * 0.125f) * tf2;
            float e3 = __expf(acc[3] * 0.125f) * tf3;
            rs += (e0 + e1) + (e2 + e3);
            unsigned u = __builtin_amdgcn_cvt_pk_fp8_f32(e0, e1, 0, false);
            u = (unsigned)__builtin_amdgcn_cvt_pk_fp8_f32(e2, e3, (int)u, true);
            *(unsigned*)&P[l16][kbase] = u;
        }
    }
    rs += __shfl_xor(rs, 16);
    rs += __shfl_xor(rs, 32);
    if (lane < 16) comb[ph][l16] = rs;
    __syncthreads();
    if (t < 16) {
        float s = 0.f;
        #pragma unroll
        for (int w = 0; w < 8; w++) s += comb[w][t];
        inv_lds[t] = 1.0f / s;
    }
    __syncthreads();

    // ---------------- pass 2: fp8 PV MFMA + coalesced a_out store -------------
    const unsigned char* Vb0 = vtb8 + ((size_t)bh * 64 + l16) * NE;
    f32x4 accp[4];
    {
        f32x4 z4 = {0.f, 0.f, 0.f, 0.f};
        #pragma unroll
        for (int c = 0; c < 4; c++) accp[c] = z4;
    }
    #pragma unroll 1
    for (int j = 0; j < 4; j++) {
        int n0 = (ph + 8 * j) * 64;
        long long vb0[4], vb1[4];
        #pragma unroll
        for (int c = 0; c < 4; c++) {
            const unsigned char* Vb = Vb0 + (size_t)c * 16 * NE + n0 + g * 8;
            vb0[c] = *(const long long*)(Vb);
            vb1[c] = *(const long long*)(Vb + 32);
        }
        long long pa0 = *(const long long*)&P[l16][n0 + g * 8];
        long long pa1 = *(const long long*)&P[l16][n0 + 32 + g * 8];
        #pragma unroll
        for (int c = 0; c < 4; c++) {
            accp[c] = mfma8(pa0, vb0[c], accp[c]);
            accp[c] = mfma8(pa1, vb1[c], accp[c]);
        }
        #pragma unroll
        for (int r4 = 0; r4 < 4; r4++) {
            int row = r4 * 4 + g;
            unsigned u = *(const unsigned*)&P[row][n0 + l16 * 4];
            float iv = inv_lds[row];
            f32x4 o;
            o[0] = __builtin_amdgcn_cvt_f32_fp8((int)u, 0) * iv;
            o[1] = __builtin_amdgcn_cvt_f32_fp8((int)u, 1) * iv;
            o[2] = __builtin_amdgcn_cvt_f32_fp8((int)u, 2) * iv;
            o[3] = __builtin_amdgcn_cvt_f32_fp8((int)u, 3) * iv;
            *(f32x4*)&a_out[((size_t)bh * NE + m0 + row) * NE + n0 + l16 * 4] = o;
        }
    }

    // ---------------- combine PV partials across 8 waves (alias P) ------------
    __syncthreads();
    float (*pvcomb)[16][64] = (float (*)[16][64])&P[0][0];  // 28.7 KB <= 33 KB
    if (ph > 0) {
        #pragma unroll
        for (int c = 0; c < 4; c++)
            #pragma unroll
            for (int r = 0; r < 4; r++)
                pvcomb[ph - 1][g * 4 + r][c * 16 + l16] = accp[c][r];
    }
    __syncthreads();
    if (ph == 0) {
        #pragma unroll
        for (int c = 0; c < 4; c++) {
            #pragma unroll
            for (int r = 0; r < 4; r++) {
                float v = accp[c][r];
                #pragma unroll
                for (int w = 0; w < 7; w++) v += pvcomb[w][g * 4 + r][c * 16 + l16];
                v *= inv_lds[g * 4 + r];
                oatb[(size_t)(b * NE + m0 + g * 4 + r) * 256 + h * 64 + c * 16 + l16] = f2b(v);
            }
        }
    }
}

// ---------------- fc GEMM + residual from x + transposed store ----------------
__global__ __launch_bounds__(256) void k_gemm_fc(const short* __restrict__ A,
        const short* __restrict__ W, const float* __restrict__ x,
        float* __restrict__ xout) {
    int t = threadIdx.x;
    int wv_ = t >> 6, lane = t & 63;
    int l16 = lane & 15, g = lane >> 4, lk = g * 8;
    int m0 = blockIdx.x * 64, n0 = blockIdx.y * 64;
    int mw = m0 + wv_ * 16;
    const short* Ab = A + (size_t)(mw + l16) * 256 + lk;
    const short* Wb = W + (size_t)(n0 + l16) * 256 + lk;
    f32x4 acc[4];
    f32x4 z4 = {0.f, 0.f, 0.f, 0.f};
    #pragma unroll
    for (int c = 0; c < 4; c++) acc[c] = z4;
    #pragma unroll
    for (int kk = 0; kk < 8; kk++) {
        bf16x8 av = *(const bf16x8*)(Ab + kk * 32);
        #pragma unroll
        for (int c = 0; c < 4; c++) {
            bf16x8 bv = *(const bf16x8*)(Wb + (size_t)c * 16 * 256 + kk * 32);
            acc[c] = mfma16(av, bv, acc[c]);
        }
    }
    __shared__ float tl[64][68];
    #pragma unroll
    for (int c = 0; c < 4; c++)
        #pragma unroll
        for (int r = 0; r < 4; r++)
            tl[c * 16 + l16][wv_ * 16 + g * 4 + r] = acc[c][r];
    __syncthreads();
    int b = m0 >> 11, e0 = m0 & (NE - 1);
    int dl = t >> 2, ec = (t & 3) * 16;
    #pragma unroll
    for (int i = 0; i < 4; i++) {
        size_t idx = ((size_t)b * ND + n0 + dl) * NE + e0 + ec + i * 4;
        f32x4 xv = *(const f32x4*)&x[idx];
        f32x4 v = *(f32x4*)&tl[dl][ec + i * 4];
        v[0] += xv[0]; v[1] += xv[1]; v[2] += xv[2]; v[3] += xv[3];
        *(f32x4*)&xout[idx] = v;
    }
}

extern "C" void kernel_launch(void* const* d_in, const int* in_sizes, int n_in,
                              void* d_out, int out_size, void* d_ws, size_t ws_size,
                              hipStream_t stream) {
    const float* x    = (const float*)d_in[0];
    const int*   dist = (const int*)d_in[1];
    const float* w_qs = (const float*)d_in[2];
    const float* w_ks = (const float*)d_in[3];
    const float* w_vs = (const float*)d_in[4];
    const float* w_fc = (const float*)d_in[5];
    const float* w_rpr= (const float*)d_in[6];
    const float* ln_g = (const float*)d_in[7];
    const float* ln_b = (const float*)d_in[8];

    char* ws = (char*)d_ws;
    short* sbf  = (short*)(ws);                            // 2 MB
    short* qnb  = (short*)(ws + (2u  << 20));              // 2 MB
    unsigned char* qf8  = (unsigned char*)(ws + (4u << 20));   // 1 MB
    unsigned char* kf8  = (unsigned char*)(ws + (5u << 20));   // 1 MB
    unsigned char* vtb8 = (unsigned char*)(ws + (6u << 20));   // 1 MB
    short* oatb = (short*)(ws + (7u  << 20));              // 2 MB
    uint4* qdrT8 = (uint4*)(ws + (9u << 20));              // 256 KB
    unsigned char* d8 = (unsigned char*)(ws + (10u << 20)); // 8.4 MB
    short* wqsb = (short*)(ws + (19u << 20));
    short* wksb = (short*)(ws + (19u << 20) + 131072);
    short* wvsb = (short*)(ws + (19u << 20) + 262144);
    short* wfcb = (short*)(ws + (19u << 20) + 393216);

    float* xout  = (float*)d_out;
    float* a_out = xout + (size_t)NB * ND * NE;

    k_cvt_all<<<dim3(256), dim3(256), 0, stream>>>(w_qs, w_ks, w_vs, w_fc,
                                                   wqsb, wksb, wvsb, wfcb);
    k_d8<<<dim3(NB * NE * NE / 4 / 256), dim3(256), 0, stream>>>(dist, d8);
    k_prep<<<dim3(NE / 32, NB), dim3(256), 0, stream>>>(x, ln_g, ln_b, sbf, qnb);
    k_gemm_qkv<<<dim3(64, 4, 3), dim3(256), 0, stream>>>(qnb, sbf, wqsb, wksb, wvsb,
                                                         w_rpr, qf8, kf8, vtb8, qdrT8);
    k_attn<<<dim3(NE / 16, NB * NH), dim3(512), 0, stream>>>(qf8, kf8, d8, qdrT8,
                                                             vtb8, a_out, oatb);
    k_gemm_fc<<<dim3(64, 4), dim3(256), 0, stream>>>(oatb, wfcb, x, xout);
}

// Round 14
// 87.391 us; speedup vs baseline: 1.5884x; 1.4804x over previous
//
#include <hip/hip_runtime.h>
#include <hip/hip_bf16.h>

#define NB 2
#define ND 256
#define NE 2048
#define NH 4
#define MAXP 8
#define PSTR8 2064   // LDS P row stride (bytes)

typedef __attribute__((ext_vector_type(8))) short bf16x8;
typedef __attribute__((ext_vector_type(4))) float f32x4;

static __device__ __forceinline__ short f2b(float f) {
    union { __hip_bfloat16 h; short s; } u;
    u.h = __float2bfloat16(f);
    return u.s;
}

static __device__ __forceinline__ f32x4 mfma16(bf16x8 a, bf16x8 b, f32x4 c) {
    return __builtin_amdgcn_mfma_f32_16x16x32_bf16(a, b, c, 0, 0, 0);
}

static __device__ __forceinline__ f32x4 mfma8(long long a, long long b, f32x4 c) {
    return __builtin_amdgcn_mfma_f32_16x16x32_fp8_fp8(a, b, c, 0, 0, 0);
}

static __device__ __forceinline__ unsigned char f2fp8(float f) {
    return (unsigned char)(__builtin_amdgcn_cvt_pk_fp8_f32(f, 0.f, 0, false) & 0xFF);
}

// ---------------- f32 -> bf16 convert, all 4 weight matrices ----------------
__global__ __launch_bounds__(256) void k_cvt_all(const float* __restrict__ w0,
        const float* __restrict__ w1, const float* __restrict__ w2,
        const float* __restrict__ w3, short* __restrict__ o0,
        short* __restrict__ o1, short* __restrict__ o2, short* __restrict__ o3) {
    int which = blockIdx.x >> 6;
    int i = (blockIdx.x & 63) * 256 + threadIdx.x;
    const float* in = which == 0 ? w0 : which == 1 ? w1 : which == 2 ? w2 : w3;
    short* out = which == 0 ? o0 : which == 1 ? o1 : which == 2 ? o2 : o3;
    f32x4 v = ((const f32x4*)in)[i];
    short4 o;
    o.x = f2b(v[0]); o.y = f2b(v[1]); o.z = f2b(v[2]); o.w = f2b(v[3]);
    ((short4*)out)[i] = o;
}

// ---------------- dist -> packed d8p tiles ----------------
// grid (NE/16, NB), 512 thr. d8p[b][strip][colblk=32][c=4][(g*16+l16)*4] u8,
// value = min(dist[b][strip*16+l16][colblk*64+c*16+g*4+k], 9).
__global__ __launch_bounds__(512) void k_d8(const int* __restrict__ dist,
        unsigned char* __restrict__ d8p) {
    __shared__ unsigned char L[16][2064];
    int b = blockIdx.y, strip = blockIdx.x;
    int t = threadIdx.x;
    const int* base = dist + ((size_t)b * NE + strip * 16) * NE;
    #pragma unroll
    for (int row = 0; row < 16; row++) {
        int4 v = *(const int4*)&base[(size_t)row * NE + t * 4];
        uchar4 o;
        o.x = (unsigned char)(v.x < 9 ? v.x : 9);
        o.y = (unsigned char)(v.y < 9 ? v.y : 9);
        o.z = (unsigned char)(v.z < 9 ? v.z : 9);
        o.w = (unsigned char)(v.w < 9 ? v.w : 9);
        *(uchar4*)&L[row][t * 4] = o;
    }
    __syncthreads();
    unsigned char* out = d8p + ((size_t)(b * 128 + strip)) * 32768;
    #pragma unroll
    for (int i = 0; i < 16; i++) {
        int w = i * 512 + t;
        int colblk = w >> 8;
        int rem = w & 255;
        int c = rem >> 6, lane6 = rem & 63;
        int g = lane6 >> 4, l16 = lane6 & 15;
        uchar4 val = *(const uchar4*)&L[l16][colblk * 64 + c * 16 + g * 4];
        *(uchar4*)&out[(size_t)w * 4] = val;
    }
}

// ---------------- fused transpose + layernorm: x [B,D,E] -> sbf, qnb ----------
__global__ __launch_bounds__(256) void k_prep(const float* __restrict__ x,
        const float* __restrict__ g, const float* __restrict__ bb,
        short* __restrict__ sbf, short* __restrict__ qnb) {
    __shared__ float tileT[32][257];
    int b = blockIdx.y;
    int e0 = blockIdx.x * 32;
    int t = threadIdx.x;
    int tx = t & 31, ty = t >> 5; // 32 x 8
    #pragma unroll
    for (int d0 = 0; d0 < 256; d0 += 32) {
        #pragma unroll
        for (int r = 0; r < 4; r++) {
            int dd = d0 + ty + r * 8;
            tileT[tx][dd] = x[((size_t)b * ND + dd) * NE + e0 + tx];
        }
    }
    __syncthreads();
    int wave = t >> 6, lane = t & 63;
    #pragma unroll 1
    for (int rr = 0; rr < 8; rr++) {
        int e = wave * 8 + rr;
        float v0 = tileT[e][lane], v1 = tileT[e][lane + 64];
        float v2 = tileT[e][lane + 128], v3 = tileT[e][lane + 192];
        float sum = (v0 + v1) + (v2 + v3);
        #pragma unroll
        for (int off = 32; off; off >>= 1) sum += __shfl_xor(sum, off);
        float mean = sum * (1.0f / ND);
        float d0 = v0 - mean, d1 = v1 - mean, d2 = v2 - mean, d3 = v3 - mean;
        float sq = (d0 * d0 + d1 * d1) + (d2 * d2 + d3 * d3);
        #pragma unroll
        for (int off = 32; off; off >>= 1) sq += __shfl_xor(sq, off);
        float inv = rsqrtf(sq * (1.0f / ND) + 1e-6f);
        size_t base = ((size_t)b * NE + e0 + e) * ND;
        sbf[base + lane]       = f2b(v0);
        sbf[base + lane + 64]  = f2b(v1);
        sbf[base + lane + 128] = f2b(v2);
        sbf[base + lane + 192] = f2b(v3);
        qnb[base + lane]       = f2b(d0 * inv * g[lane]       + bb[lane]);
        qnb[base + lane + 64]  = f2b(d1 * inv * g[lane + 64]  + bb[lane + 64]);
        qnb[base + lane + 128] = f2b(d2 * inv * g[lane + 128] + bb[lane + 128]);
        qnb[base + lane + 192] = f2b(d3 * inv * g[lane + 192] + bb[lane + 192]);
    }
}

// ---------------- merged QKV MFMA GEMM ----------------
// z=0 q->qf8 row-major + qdrT8; z=1 k->kp8 packed; z=2 v->vp8 packed.
// kp8[b][h][rowblk=128][kk=2][l16*32+g*8]  (1 KB per rowblk)
// vp8[b][h][eblk=32][dvblk=4][kk=2][l16*32+g*8]  (4 KB per eblk)
__global__ __launch_bounds__(256) void k_gemm_qkv(const short* __restrict__ qnb,
        const short* __restrict__ sbf, const short* __restrict__ wq,
        const short* __restrict__ wk, const short* __restrict__ wv,
        const float* __restrict__ w_rpr, unsigned char* __restrict__ qf8,
        unsigned char* __restrict__ kp8, unsigned char* __restrict__ vp8,
        uint4* __restrict__ qdrT8) {
    int z = blockIdx.z;
    const short* A = z == 0 ? qnb : sbf;
    const short* W = z == 0 ? wq : z == 1 ? wk : wv;
    int t = threadIdx.x;
    int wv_ = t >> 6, lane = t & 63;
    int l16 = lane & 15, g = lane >> 4, lk = g * 8;
    int m0 = blockIdx.x * 64;
    int h = blockIdx.y;
    int n0 = h * 64;
    int mw = m0 + wv_ * 16;
    const short* Ab = A + (size_t)(mw + l16) * 256 + lk;
    const short* Wb = W + (size_t)(n0 + l16) * 256 + lk;
    __shared__ float wr[9][64];
    if (z == 0) {
        for (int i = t; i < 576; i += 256) wr[i >> 6][i & 63] = w_rpr[i];
    }
    f32x4 acc[4];
    f32x4 z4 = {0.f, 0.f, 0.f, 0.f};
    #pragma unroll
    for (int c = 0; c < 4; c++) acc[c] = z4;
    #pragma unroll
    for (int kk = 0; kk < 8; kk++) {
        bf16x8 av = *(const bf16x8*)(Ab + kk * 32);
        #pragma unroll
        for (int c = 0; c < 4; c++) {
            bf16x8 bv = *(const bf16x8*)(Wb + (size_t)c * 16 * 256 + kk * 32);
            acc[c] = mfma16(av, bv, acc[c]);
        }
    }
    int b = m0 >> 11;
    if (z == 0) {
        __syncthreads();   // wr ready
        #pragma unroll
        for (int r = 0; r < 4; r++) {
            float tv[9];
            #pragma unroll
            for (int p = 0; p < 9; p++) {
                float v = acc[0][r] * wr[p][l16] + acc[1][r] * wr[p][16 + l16]
                        + acc[2][r] * wr[p][32 + l16] + acc[3][r] * wr[p][48 + l16];
                v += __shfl_xor(v, 1); v += __shfl_xor(v, 2);
                v += __shfl_xor(v, 4); v += __shfl_xor(v, 8);
                tv[p] = __expf(v * 0.125f);
            }
            if (l16 == 0) {
                unsigned lo = __builtin_amdgcn_cvt_pk_fp8_f32(tv[0], tv[1], 0, false);
                lo = (unsigned)__builtin_amdgcn_cvt_pk_fp8_f32(tv[2], tv[3], (int)lo, true);
                unsigned hi = __builtin_amdgcn_cvt_pk_fp8_f32(tv[4], tv[5], 0, false);
                hi = (unsigned)__builtin_amdgcn_cvt_pk_fp8_f32(tv[6], tv[7], (int)hi, true);
                uint4 o;
                o.x = lo; o.y = hi;
                o.z = (unsigned)__float_as_int(tv[8]);
                o.w = 0u;
                qdrT8[(size_t)(mw + g * 4 + r) * NH + h] = o;
            }
        }
        __shared__ unsigned char ftq[64][80];
        #pragma unroll
        for (int c = 0; c < 4; c++)
            #pragma unroll
            for (int r = 0; r < 4; r++)
                ftq[wv_ * 16 + g * 4 + r][c * 16 + l16] = f2fp8(acc[c][r]);
        __syncthreads();
        int row = t >> 2, colq = (t & 3) * 16;
        uint4 v = *(const uint4*)&ftq[row][colq];
        *(uint4*)&qf8[(size_t)(m0 + row) * 256 + n0 + colq] = v;
    } else if (z == 1) {
        __shared__ unsigned char ft[64][80];
        #pragma unroll
        for (int c = 0; c < 4; c++)
            #pragma unroll
            for (int r = 0; r < 4; r++)
                ft[wv_ * 16 + g * 4 + r][c * 16 + l16] = f2fp8(acc[c][r]);
        __syncthreads();
        int rb_local = t >> 6;
        size_t rbase = ((size_t)(b * NH + h) * 128 + ((m0 & (NE - 1)) >> 4) + rb_local) * 1024;
        *(long long*)&kp8[rbase + l16 * 32 + g * 8] =
            *(const long long*)&ft[rb_local * 16 + l16][g * 8];
        *(long long*)&kp8[rbase + 512 + l16 * 32 + g * 8] =
            *(const long long*)&ft[rb_local * 16 + l16][32 + g * 8];
    } else {
        __shared__ unsigned char vt[64][72];
        #pragma unroll
        for (int c = 0; c < 4; c++)
            #pragma unroll
            for (int r = 0; r < 4; r++)
                vt[c * 16 + l16][wv_ * 16 + g * 4 + r] = f2fp8(acc[c][r]);
        __syncthreads();
        int eblk = (m0 & (NE - 1)) >> 6;
        size_t vbase = ((size_t)(b * NH + h) * 32 + eblk) * 4096;
        int dvb = t >> 7, sub = t & 127;
        int kk = sub >> 6, ln = sub & 63;
        int vl16 = ln & 15, vg = ln >> 4;
        #pragma unroll
        for (int dd = 0; dd < 2; dd++) {
            int dvblk = dvb + dd * 2;
            *(long long*)&vp8[vbase + (dvblk * 2 + kk) * 512 + vl16 * 32 + vg * 8] =
                *(const long long*)&vt[dvblk * 16 + vl16][kk * 32 + vg * 8];
        }
    }
}

// ---------------- fused scores+softmax+PV; packed operands ------------------
// grid (NE/16, NB*NH), block 512 (8 waves). Wave ph owns tiles n0=(ph+8j)*64.
// All wave loads are contiguous: K/V 512B (8 lines), d8 256B (4 lines).
__global__ __launch_bounds__(512, 4) void k_attn(
        const unsigned char* __restrict__ qf8, const unsigned char* __restrict__ kp8,
        const unsigned char* __restrict__ d8p, const uint4* __restrict__ qdrT8,
        const unsigned char* __restrict__ vp8, float* __restrict__ a_out,
        short* __restrict__ oatb) {
    __shared__ __align__(16) unsigned char P[16][PSTR8];  // 33.0 KB fp8
    __shared__ float comb[8][16];
    __shared__ float inv_lds[16];

    int t = threadIdx.x;
    int ph = t >> 6, lane = t & 63;
    int l16 = lane & 15, g = lane >> 4;
    int bh = blockIdx.y, b = bh >> 2, h = bh & 3;
    int m0 = blockIdx.x * 16;
    int lane32 = l16 * 32 + g * 8;
    int lane4 = (g * 16 + l16) * 4;

    // per-lane T LUT for q-row l16
    uint4 tw = qdrT8[(size_t)(b * NE + m0 + l16) * NH + h];
    unsigned Tlo = tw.x, Thi = tw.y;
    float T8f = __int_as_float((int)tw.z);

    const unsigned char* Qb = qf8 + (size_t)(b * NE + m0 + l16) * 256 + h * 64 + g * 8;
    long long aq0 = *(const long long*)(Qb);
    long long aq1 = *(const long long*)(Qb + 32);

    const unsigned char* Kp = kp8 + (size_t)(b * NH + h) * 131072;
    const unsigned char* Vp = vp8 + (size_t)(b * NH + h) * 131072;
    const unsigned char* Dp = d8p + (size_t)(b * 128 + (m0 >> 4)) * 32768;

    float rs = 0.f;

    // ---------------- pass 1: fp8 QK^T -> exp -> fp8 P, row sums --------------
    unsigned selc[4], seln[4];
    #pragma unroll
    for (int c = 0; c < 4; c++)
        selc[c] = *(const unsigned*)&Dp[ph * 1024 + c * 256 + lane4];
    #pragma unroll 1
    for (int j = 0; j < 4; j++) {
        int n0blk = ph + 8 * j;
        int n0 = n0blk * 64;
        if (j < 3) {
            #pragma unroll
            for (int c = 0; c < 4; c++)
                seln[c] = *(const unsigned*)&Dp[(n0blk + 8) * 1024 + c * 256 + lane4];
        }
        #pragma unroll
        for (int c = 0; c < 4; c++) {
            const unsigned char* Bb = Kp + (size_t)(n0blk * 4 + c) * 1024 + lane32;
            long long kv0 = *(const long long*)(Bb);
            long long kv1 = *(const long long*)(Bb + 512);
            f32x4 acc = {0.f, 0.f, 0.f, 0.f};
            acc = mfma8(kv0, aq0, acc);
            acc = mfma8(kv1, aq1, acc);
            int kbase = n0 + c * 16 + g * 4;
            unsigned sel = selc[c];
            unsigned tpk = __builtin_amdgcn_perm(Thi, Tlo, sel);
            float tf0 = __builtin_amdgcn_cvt_f32_fp8((int)tpk, 0);
            float tf1 = __builtin_amdgcn_cvt_f32_fp8((int)tpk, 1);
            float tf2 = __builtin_amdgcn_cvt_f32_fp8((int)tpk, 2);
            float tf3 = __builtin_amdgcn_cvt_f32_fp8((int)tpk, 3);
            unsigned db0 = sel & 0xFFu;
            unsigned db1 = (sel >> 8) & 0xFFu;
            unsigned db2 = (sel >> 16) & 0xFFu;
            unsigned db3 = (sel >> 24) & 0xFFu;
            tf0 = db0 < 8 ? tf0 : (db0 == 8 ? T8f : 0.f);
            tf1 = db1 < 8 ? tf1 : (db1 == 8 ? T8f : 0.f);
            tf2 = db2 < 8 ? tf2 : (db2 == 8 ? T8f : 0.f);
            tf3 = db3 < 8 ? tf3 : (db3 == 8 ? T8f : 0.f);
            float e0 = __expf(acc[0] * 0.125f) * tf0;
            float e1 = __expf(acc[1] * 0.125f) * tf1;
            float e2 = __expf(acc[2] * 0.125f) * tf2;
            float e3 = __expf(acc[3] * 0.125f) * tf3;
            rs += (e0 + e1) + (e2 + e3);
            unsigned u = __builtin_amdgcn_cvt_pk_fp8_f32(e0, e1, 0, false);
            u = (unsigned)__builtin_amdgcn_cvt_pk_fp8_f32(e2, e3, (int)u, true);
            *(unsigned*)&P[l16][kbase] = u;
        }
        #pragma unroll
        for (int c = 0; c < 4; c++) selc[c] = seln[c];
    }
    rs += __shfl_xor(rs, 16);
    rs += __shfl_xor(rs, 32);
    if (lane < 16) comb[ph][l16] = rs;
    __syncthreads();
    if (t < 16) {
        float s = 0.f;
        #pragma unroll
        for (int w = 0; w < 8; w++) s += comb[w][t];
        inv_lds[t] = 1.0f / s;
    }
    __syncthreads();

    // ---------------- pass 2: fp8 PV MFMA + coalesced a_out store -------------
    f32x4 accp[4];
    {
        f32x4 z4 = {0.f, 0.f, 0.f, 0.f};
        #pragma unroll
        for (int c = 0; c < 4; c++) accp[c] = z4;
    }
    #pragma unroll 1
    for (int j = 0; j < 4; j++) {
        int eblk = ph + 8 * j;
        int n0 = eblk * 64;
        long long vb0[4], vb1[4];
        #pragma unroll
        for (int c = 0; c < 4; c++) {
            const unsigned char* Vb = Vp + (size_t)eblk * 4096 + (c * 2) * 512 + lane32;
            vb0[c] = *(const long long*)(Vb);
            vb1[c] = *(const long long*)(Vb + 512);
        }
        long long pa0 = *(const long long*)&P[l16][n0 + g * 8];
        long long pa1 = *(const long long*)&P[l16][n0 + 32 + g * 8];
        #pragma unroll
        for (int c = 0; c < 4; c++) {
            accp[c] = mfma8(pa0, vb0[c], accp[c]);
            accp[c] = mfma8(pa1, vb1[c], accp[c]);
        }
        #pragma unroll
        for (int r4 = 0; r4 < 4; r4++) {
            int row = r4 * 4 + g;
            unsigned u = *(const unsigned*)&P[row][n0 + l16 * 4];
            float iv = inv_lds[row];
            f32x4 o;
            o[0] = __builtin_amdgcn_cvt_f32_fp8((int)u, 0) * iv;
            o[1] = __builtin_amdgcn_cvt_f32_fp8((int)u, 1) * iv;
            o[2] = __builtin_amdgcn_cvt_f32_fp8((int)u, 2) * iv;
            o[3] = __builtin_amdgcn_cvt_f32_fp8((int)u, 3) * iv;
            *(f32x4*)&a_out[((size_t)bh * NE + m0 + row) * NE + n0 + l16 * 4] = o;
        }
    }

    // ---------------- combine PV partials across 8 waves (alias P) ------------
    __syncthreads();
    float (*pvcomb)[16][64] = (float (*)[16][64])&P[0][0];  // 28.7 KB <= 33 KB
    if (ph > 0) {
        #pragma unroll
        for (int c = 0; c < 4; c++)
            #pragma unroll
            for (int r = 0; r < 4; r++)
                pvcomb[ph - 1][g * 4 + r][c * 16 + l16] = accp[c][r];
    }
    __syncthreads();
    if (ph == 0) {
        #pragma unroll
        for (int c = 0; c < 4; c++) {
            #pragma unroll
            for (int r = 0; r < 4; r++) {
                float v = accp[c][r];
                #pragma unroll
                for (int w = 0; w < 7; w++) v += pvcomb[w][g * 4 + r][c * 16 + l16];
                v *= inv_lds[g * 4 + r];
                oatb[(size_t)(b * NE + m0 + g * 4 + r) * 256 + h * 64 + c * 16 + l16] = f2b(v);
            }
        }
    }
}

// ---------------- fc GEMM + residual from x + transposed store ----------------
__global__ __launch_bounds__(256) void k_gemm_fc(const short* __restrict__ A,
        const short* __restrict__ W, const float* __restrict__ x,
        float* __restrict__ xout) {
    int t = threadIdx.x;
    int wv_ = t >> 6, lane = t & 63;
    int l16 = lane & 15, g = lane >> 4, lk = g * 8;
    int m0 = blockIdx.x * 64, n0 = blockIdx.y * 64;
    int mw = m0 + wv_ * 16;
    const short* Ab = A + (size_t)(mw + l16) * 256 + lk;
    const short* Wb = W + (size_t)(n0 + l16) * 256 + lk;
    f32x4 acc[4];
    f32x4 z4 = {0.f, 0.f, 0.f, 0.f};
    #pragma unroll
    for (int c = 0; c < 4; c++) acc[c] = z4;
    #pragma unroll
    for (int kk = 0; kk < 8; kk++) {
        bf16x8 av = *(const bf16x8*)(Ab + kk * 32);
        #pragma unroll
        for (int c = 0; c < 4; c++) {
            bf16x8 bv = *(const bf16x8*)(Wb + (size_t)c * 16 * 256 + kk * 32);
            acc[c] = mfma16(av, bv, acc[c]);
        }
    }
    __shared__ float tl[64][68];
    #pragma unroll
    for (int c = 0; c < 4; c++)
        #pragma unroll
        for (int r = 0; r < 4; r++)
            tl[c * 16 + l16][wv_ * 16 + g * 4 + r] = acc[c][r];
    __syncthreads();
    int b = m0 >> 11, e0 = m0 & (NE - 1);
    int dl = t >> 2, ec = (t & 3) * 16;
    #pragma unroll
    for (int i = 0; i < 4; i++) {
        size_t idx = ((size_t)b * ND + n0 + dl) * NE + e0 + ec + i * 4;
        f32x4 xv = *(const f32x4*)&x[idx];
        f32x4 v = *(f32x4*)&tl[dl][ec + i * 4];
        v[0] += xv[0]; v[1] += xv[1]; v[2] += xv[2]; v[3] += xv[3];
        *(f32x4*)&xout[idx] = v;
    }
}

extern "C" void kernel_launch(void* const* d_in, const int* in_sizes, int n_in,
                              void* d_out, int out_size, void* d_ws, size_t ws_size,
                              hipStream_t stream) {
    const float* x    = (const float*)d_in[0];
    const int*   dist = (const int*)d_in[1];
    const float* w_qs = (const float*)d_in[2];
    const float* w_ks = (const float*)d_in[3];
    const float* w_vs = (const float*)d_in[4];
    const float* w_fc = (const float*)d_in[5];
    const float* w_rpr= (const float*)d_in[6];
    const float* ln_g = (const float*)d_in[7];
    const float* ln_b = (const float*)d_in[8];

    char* ws = (char*)d_ws;
    short* sbf  = (short*)(ws);                            // 2 MB
    short* qnb  = (short*)(ws + (2u  << 20));              // 2 MB
    unsigned char* qf8  = (unsigned char*)(ws + (4u << 20));   // 1 MB
    unsigned char* kp8  = (unsigned char*)(ws + (5u << 20));   // 1 MB
    unsigned char* vp8  = (unsigned char*)(ws + (6u << 20));   // 1 MB
    short* oatb = (short*)(ws + (7u  << 20));              // 2 MB
    uint4* qdrT8 = (uint4*)(ws + (9u << 20));              // 256 KB
    unsigned char* d8p = (unsigned char*)(ws + (10u << 20)); // 8.4 MB
    short* wqsb = (short*)(ws + (19u << 20));
    short* wksb = (short*)(ws + (19u << 20) + 131072);
    short* wvsb = (short*)(ws + (19u << 20) + 262144);
    short* wfcb = (short*)(ws + (19u << 20) + 393216);

    float* xout  = (float*)d_out;
    float* a_out = xout + (size_t)NB * ND * NE;

    k_cvt_all<<<dim3(256), dim3(256), 0, stream>>>(w_qs, w_ks, w_vs, w_fc,
                                                   wqsb, wksb, wvsb, wfcb);
    k_d8<<<dim3(NE / 16, NB), dim3(512), 0, stream>>>(dist, d8p);
    k_prep<<<dim3(NE / 32, NB), dim3(256), 0, stream>>>(x, ln_g, ln_b, sbf, qnb);
    k_gemm_qkv<<<dim3(64, 4, 3), dim3(256), 0, stream>>>(qnb, sbf, wqsb, wksb, wvsb,
                                                         w_rpr, qf8, kp8, vp8, qdrT8);
    k_attn<<<dim3(NE / 16, NB * NH), dim3(512), 0, stream>>>(qf8, kp8, d8p, qdrT8,
                                                             vp8, a_out, oatb);
    k_gemm_fc<<<dim3(64, 4), dim3(256), 0, stream>>>(oatb, wfcb, x, xout);
}

// Round 15
// 78.102 us; speedup vs baseline: 1.7773x; 1.1189x over previous
//
#include <hip/hip_runtime.h>
#include <hip/hip_bf16.h>

#define NB 2
#define ND 256
#define NE 2048
#define NH 4
#define MAXP 8
#define PSTR8 2064   // LDS P row stride (bytes)

typedef __attribute__((ext_vector_type(8))) short bf16x8;
typedef __attribute__((ext_vector_type(4))) float f32x4;

static __device__ __forceinline__ short f2b(float f) {
    union { __hip_bfloat16 h; short s; } u;
    u.h = __float2bfloat16(f);
    return u.s;
}

static __device__ __forceinline__ f32x4 mfma16(bf16x8 a, bf16x8 b, f32x4 c) {
    return __builtin_amdgcn_mfma_f32_16x16x32_bf16(a, b, c, 0, 0, 0);
}

static __device__ __forceinline__ f32x4 mfma8(long long a, long long b, f32x4 c) {
    return __builtin_amdgcn_mfma_f32_16x16x32_fp8_fp8(a, b, c, 0, 0, 0);
}

static __device__ __forceinline__ unsigned char f2fp8(float f) {
    return (unsigned char)(__builtin_amdgcn_cvt_pk_fp8_f32(f, 0.f, 0, false) & 0xFF);
}

// ---------------- front: d8 pack (blk<256) | weight cvt (256..383) | prep (384..447) --
// all 512 threads.
__global__ __launch_bounds__(512) void k_front(const int* __restrict__ dist,
        unsigned char* __restrict__ d8p,
        const float* __restrict__ w_qs, const float* __restrict__ w_ks,
        const float* __restrict__ w_vs, const float* __restrict__ w_fc,
        short* __restrict__ wqsb, short* __restrict__ wksb,
        short* __restrict__ wvsb, short* __restrict__ wfcb,
        const float* __restrict__ x, const float* __restrict__ g_,
        const float* __restrict__ bb, short* __restrict__ sbf,
        short* __restrict__ qnb) {
    __shared__ __align__(16) char fbuf[33024];
    int blk = blockIdx.x;
    int t = threadIdx.x;
    if (blk < 256) {
        // ---- dist -> packed d8p tiles ----
        unsigned char (*L)[2064] = (unsigned char (*)[2064])fbuf;
        int b = blk >> 7, strip = blk & 127;
        const int* base = dist + ((size_t)b * NE + strip * 16) * NE;
        #pragma unroll
        for (int row = 0; row < 16; row++) {
            int4 v = *(const int4*)&base[(size_t)row * NE + t * 4];
            uchar4 o;
            o.x = (unsigned char)(v.x < 9 ? v.x : 9);
            o.y = (unsigned char)(v.y < 9 ? v.y : 9);
            o.z = (unsigned char)(v.z < 9 ? v.z : 9);
            o.w = (unsigned char)(v.w < 9 ? v.w : 9);
            *(uchar4*)&L[row][t * 4] = o;
        }
        __syncthreads();
        unsigned char* out = d8p + ((size_t)(b * 128 + strip)) * 32768;
        #pragma unroll
        for (int i = 0; i < 16; i++) {
            int w = i * 512 + t;
            int colblk = w >> 8;
            int rem = w & 255;
            int c = rem >> 6, lane6 = rem & 63;
            int g = lane6 >> 4, l16 = lane6 & 15;
            uchar4 val = *(const uchar4*)&L[l16][colblk * 64 + c * 16 + g * 4];
            *(uchar4*)&out[(size_t)w * 4] = val;
        }
    } else if (blk < 384) {
        // ---- f32 -> bf16 weights (4 x 65536 floats, float4/thread) ----
        int i = (blk - 256) * 512 + t;          // float4 index, 0..65535
        int which = i >> 14;
        int idx = i & 16383;
        const float* in = which == 0 ? w_qs : which == 1 ? w_ks : which == 2 ? w_vs : w_fc;
        short* out = which == 0 ? wqsb : which == 1 ? wksb : which == 2 ? wvsb : wfcb;
        f32x4 v = ((const f32x4*)in)[idx];
        short4 o;
        o.x = f2b(v[0]); o.y = f2b(v[1]); o.z = f2b(v[2]); o.w = f2b(v[3]);
        ((short4*)out)[idx] = o;
    } else {
        // ---- transpose + layernorm: 32 e-rows per block, 512 thr ----
        float (*tileT)[257] = (float (*)[257])fbuf;
        int blk2 = blk - 384;
        int b = blk2 >> 6;                      // 64 blocks per b
        int e0 = (blk2 & 63) * 32;
        int tx = t & 31, ty = t >> 5;           // 32 x 16
        #pragma unroll
        for (int d0 = 0; d0 < 256; d0 += 32) {
            #pragma unroll
            for (int r = 0; r < 2; r++) {
                int dd = d0 + ty + r * 16;
                tileT[tx][dd] = x[((size_t)b * ND + dd) * NE + e0 + tx];
            }
        }
        __syncthreads();
        int wave = t >> 6, lane = t & 63;
        #pragma unroll 1
        for (int rr = 0; rr < 4; rr++) {
            int e = wave * 4 + rr;
            float v0 = tileT[e][lane], v1 = tileT[e][lane + 64];
            float v2 = tileT[e][lane + 128], v3 = tileT[e][lane + 192];
            float sum = (v0 + v1) + (v2 + v3);
            #pragma unroll
            for (int off = 32; off; off >>= 1) sum += __shfl_xor(sum, off);
            float mean = sum * (1.0f / ND);
            float d0 = v0 - mean, d1 = v1 - mean, d2 = v2 - mean, d3 = v3 - mean;
            float sq = (d0 * d0 + d1 * d1) + (d2 * d2 + d3 * d3);
            #pragma unroll
            for (int off = 32; off; off >>= 1) sq += __shfl_xor(sq, off);
            float inv = rsqrtf(sq * (1.0f / ND) + 1e-6f);
            size_t base = ((size_t)b * NE + e0 + e) * ND;
            sbf[base + lane]       = f2b(v0);
            sbf[base + lane + 64]  = f2b(v1);
            sbf[base + lane + 128] = f2b(v2);
            sbf[base + lane + 192] = f2b(v3);
            qnb[base + lane]       = f2b(d0 * inv * g_[lane]       + bb[lane]);
            qnb[base + lane + 64]  = f2b(d1 * inv * g_[lane + 64]  + bb[lane + 64]);
            qnb[base + lane + 128] = f2b(d2 * inv * g_[lane + 128] + bb[lane + 128]);
            qnb[base + lane + 192] = f2b(d3 * inv * g_[lane + 192] + bb[lane + 192]);
        }
    }
}

// ---------------- merged QKV MFMA GEMM ----------------
// z=0 q->qf8 row-major + qdrT8; z=1 k->kp8 packed; z=2 v->vp8 packed.
// kp8[b][h][rowblk=128][kk=2][l16*32+g*8]  (1 KB per rowblk)
// vp8[b][h][eblk=32][dvblk=4][kk=2][l16*32+g*8]  (4 KB per eblk)
__global__ __launch_bounds__(256) void k_gemm_qkv(const short* __restrict__ qnb,
        const short* __restrict__ sbf, const short* __restrict__ wq,
        const short* __restrict__ wk, const short* __restrict__ wv,
        const float* __restrict__ w_rpr, unsigned char* __restrict__ qf8,
        unsigned char* __restrict__ kp8, unsigned char* __restrict__ vp8,
        uint4* __restrict__ qdrT8) {
    int z = blockIdx.z;
    const short* A = z == 0 ? qnb : sbf;
    const short* W = z == 0 ? wq : z == 1 ? wk : wv;
    int t = threadIdx.x;
    int wv_ = t >> 6, lane = t & 63;
    int l16 = lane & 15, g = lane >> 4, lk = g * 8;
    int m0 = blockIdx.x * 64;
    int h = blockIdx.y;
    int n0 = h * 64;
    int mw = m0 + wv_ * 16;
    const short* Ab = A + (size_t)(mw + l16) * 256 + lk;
    const short* Wb = W + (size_t)(n0 + l16) * 256 + lk;
    __shared__ float wr[9][64];
    if (z == 0) {
        for (int i = t; i < 576; i += 256) wr[i >> 6][i & 63] = w_rpr[i];
    }
    f32x4 acc[4];
    f32x4 z4 = {0.f, 0.f, 0.f, 0.f};
    #pragma unroll
    for (int c = 0; c < 4; c++) acc[c] = z4;
    #pragma unroll
    for (int kk = 0; kk < 8; kk++) {
        bf16x8 av = *(const bf16x8*)(Ab + kk * 32);
        #pragma unroll
        for (int c = 0; c < 4; c++) {
            bf16x8 bv = *(const bf16x8*)(Wb + (size_t)c * 16 * 256 + kk * 32);
            acc[c] = mfma16(av, bv, acc[c]);
        }
    }
    int b = m0 >> 11;
    if (z == 0) {
        __syncthreads();   // wr ready
        #pragma unroll
        for (int r = 0; r < 4; r++) {
            float tv[9];
            #pragma unroll
            for (int p = 0; p < 9; p++) {
                float v = acc[0][r] * wr[p][l16] + acc[1][r] * wr[p][16 + l16]
                        + acc[2][r] * wr[p][32 + l16] + acc[3][r] * wr[p][48 + l16];
                v += __shfl_xor(v, 1); v += __shfl_xor(v, 2);
                v += __shfl_xor(v, 4); v += __shfl_xor(v, 8);
                tv[p] = __expf(v * 0.125f);
            }
            if (l16 == 0) {
                unsigned lo = __builtin_amdgcn_cvt_pk_fp8_f32(tv[0], tv[1], 0, false);
                lo = (unsigned)__builtin_amdgcn_cvt_pk_fp8_f32(tv[2], tv[3], (int)lo, true);
                unsigned hi = __builtin_amdgcn_cvt_pk_fp8_f32(tv[4], tv[5], 0, false);
                hi = (unsigned)__builtin_amdgcn_cvt_pk_fp8_f32(tv[6], tv[7], (int)hi, true);
                uint4 o;
                o.x = lo; o.y = hi;
                o.z = (unsigned)__float_as_int(tv[8]);
                o.w = 0u;
                qdrT8[(size_t)(mw + g * 4 + r) * NH + h] = o;
            }
        }
        __shared__ unsigned char ftq[64][80];
        #pragma unroll
        for (int c = 0; c < 4; c++)
            #pragma unroll
            for (int r = 0; r < 4; r++)
                ftq[wv_ * 16 + g * 4 + r][c * 16 + l16] = f2fp8(acc[c][r]);
        __syncthreads();
        int row = t >> 2, colq = (t & 3) * 16;
        uint4 v = *(const uint4*)&ftq[row][colq];
        *(uint4*)&qf8[(size_t)(m0 + row) * 256 + n0 + colq] = v;
    } else if (z == 1) {
        __shared__ unsigned char ft[64][80];
        #pragma unroll
        for (int c = 0; c < 4; c++)
            #pragma unroll
            for (int r = 0; r < 4; r++)
                ft[wv_ * 16 + g * 4 + r][c * 16 + l16] = f2fp8(acc[c][r]);
        __syncthreads();
        int rb_local = t >> 6;
        size_t rbase = ((size_t)(b * NH + h) * 128 + ((m0 & (NE - 1)) >> 4) + rb_local) * 1024;
        *(long long*)&kp8[rbase + l16 * 32 + g * 8] =
            *(const long long*)&ft[rb_local * 16 + l16][g * 8];
        *(long long*)&kp8[rbase + 512 + l16 * 32 + g * 8] =
            *(const long long*)&ft[rb_local * 16 + l16][32 + g * 8];
    } else {
        __shared__ unsigned char vt[64][72];
        #pragma unroll
        for (int c = 0; c < 4; c++)
            #pragma unroll
            for (int r = 0; r < 4; r++)
                vt[c * 16 + l16][wv_ * 16 + g * 4 + r] = f2fp8(acc[c][r]);
        __syncthreads();
        int eblk = (m0 & (NE - 1)) >> 6;
        size_t vbase = ((size_t)(b * NH + h) * 32 + eblk) * 4096;
        int dvb = t >> 7, sub = t & 127;
        int kk = sub >> 6, ln = sub & 63;
        int vl16 = ln & 15, vg = ln >> 4;
        #pragma unroll
        for (int dd = 0; dd < 2; dd++) {
            int dvblk = dvb + dd * 2;
            *(long long*)&vp8[vbase + (dvblk * 2 + kk) * 512 + vl16 * 32 + vg * 8] =
                *(const long long*)&vt[dvblk * 16 + vl16][kk * 32 + vg * 8];
        }
    }
}

// ---------------- fused scores+softmax+PV; packed operands ------------------
// grid (NE/16, NB*NH), block 512 (8 waves). Wave ph owns tiles n0=(ph+8j)*64.
// All wave loads are contiguous: K/V 512B (8 lines), d8 256B (4 lines).
__global__ __launch_bounds__(512, 4) void k_attn(
        const unsigned char* __restrict__ qf8, const unsigned char* __restrict__ kp8,
        const unsigned char* __restrict__ d8p, const uint4* __restrict__ qdrT8,
        const unsigned char* __restrict__ vp8, float* __restrict__ a_out,
        short* __restrict__ oatb) {
    __shared__ __align__(16) unsigned char P[16][PSTR8];  // 33.0 KB fp8
    __shared__ float comb[8][16];
    __shared__ float inv_lds[16];

    int t = threadIdx.x;
    int ph = t >> 6, lane = t & 63;
    int l16 = lane & 15, g = lane >> 4;
    int bh = blockIdx.y, b = bh >> 2, h = bh & 3;
    int m0 = blockIdx.x * 16;
    int lane32 = l16 * 32 + g * 8;
    int lane4 = (g * 16 + l16) * 4;

    // per-lane T LUT for q-row l16
    uint4 tw = qdrT8[(size_t)(b * NE + m0 + l16) * NH + h];
    unsigned Tlo = tw.x, Thi = tw.y;
    float T8f = __int_as_float((int)tw.z);

    const unsigned char* Qb = qf8 + (size_t)(b * NE + m0 + l16) * 256 + h * 64 + g * 8;
    long long aq0 = *(const long long*)(Qb);
    long long aq1 = *(const long long*)(Qb + 32);

    const unsigned char* Kp = kp8 + (size_t)(b * NH + h) * 131072;
    const unsigned char* Vp = vp8 + (size_t)(b * NH + h) * 131072;
    const unsigned char* Dp = d8p + (size_t)(b * 128 + (m0 >> 4)) * 32768;

    float rs = 0.f;

    // ---------------- pass 1: fp8 QK^T -> exp -> fp8 P, row sums --------------
    unsigned selc[4], seln[4];
    #pragma unroll
    for (int c = 0; c < 4; c++)
        selc[c] = *(const unsigned*)&Dp[ph * 1024 + c * 256 + lane4];
    #pragma unroll 1
    for (int j = 0; j < 4; j++) {
        int n0blk = ph + 8 * j;
        int n0 = n0blk * 64;
        if (j < 3) {
            #pragma unroll
            for (int c = 0; c < 4; c++)
                seln[c] = *(const unsigned*)&Dp[(n0blk + 8) * 1024 + c * 256 + lane4];
        }
        #pragma unroll
        for (int c = 0; c < 4; c++) {
            const unsigned char* Bb = Kp + (size_t)(n0blk * 4 + c) * 1024 + lane32;
            long long kv0 = *(const long long*)(Bb);
            long long kv1 = *(const long long*)(Bb + 512);
            f32x4 acc = {0.f, 0.f, 0.f, 0.f};
            acc = mfma8(kv0, aq0, acc);
            acc = mfma8(kv1, aq1, acc);
            int kbase = n0 + c * 16 + g * 4;
            unsigned sel = selc[c];
            unsigned tpk = __builtin_amdgcn_perm(Thi, Tlo, sel);
            float tf0 = __builtin_amdgcn_cvt_f32_fp8((int)tpk, 0);
            float tf1 = __builtin_amdgcn_cvt_f32_fp8((int)tpk, 1);
            float tf2 = __builtin_amdgcn_cvt_f32_fp8((int)tpk, 2);
            float tf3 = __builtin_amdgcn_cvt_f32_fp8((int)tpk, 3);
            unsigned db0 = sel & 0xFFu;
            unsigned db1 = (sel >> 8) & 0xFFu;
            unsigned db2 = (sel >> 16) & 0xFFu;
            unsigned db3 = (sel >> 24) & 0xFFu;
            tf0 = db0 < 8 ? tf0 : (db0 == 8 ? T8f : 0.f);
            tf1 = db1 < 8 ? tf1 : (db1 == 8 ? T8f : 0.f);
            tf2 = db2 < 8 ? tf2 : (db2 == 8 ? T8f : 0.f);
            tf3 = db3 < 8 ? tf3 : (db3 == 8 ? T8f : 0.f);
            float e0 = __expf(acc[0] * 0.125f) * tf0;
            float e1 = __expf(acc[1] * 0.125f) * tf1;
            float e2 = __expf(acc[2] * 0.125f) * tf2;
            float e3 = __expf(acc[3] * 0.125f) * tf3;
            rs += (e0 + e1) + (e2 + e3);
            unsigned u = __builtin_amdgcn_cvt_pk_fp8_f32(e0, e1, 0, false);
            u = (unsigned)__builtin_amdgcn_cvt_pk_fp8_f32(e2, e3, (int)u, true);
            *(unsigned*)&P[l16][kbase] = u;
        }
        #pragma unroll
        for (int c = 0; c < 4; c++) selc[c] = seln[c];
    }
    rs += __shfl_xor(rs, 16);
    rs += __shfl_xor(rs, 32);
    if (lane < 16) comb[ph][l16] = rs;
    __syncthreads();
    if (t < 16) {
        float s = 0.f;
        #pragma unroll
        for (int w = 0; w < 8; w++) s += comb[w][t];
        inv_lds[t] = 1.0f / s;
    }
    __syncthreads();

    // ---------------- pass 2: fp8 PV MFMA + coalesced a_out store -------------
    f32x4 accp[4];
    {
        f32x4 z4 = {0.f, 0.f, 0.f, 0.f};
        #pragma unroll
        for (int c = 0; c < 4; c++) accp[c] = z4;
    }
    #pragma unroll 1
    for (int j = 0; j < 4; j++) {
        int eblk = ph + 8 * j;
        int n0 = eblk * 64;
        long long vb0[4], vb1[4];
        #pragma unroll
        for (int c = 0; c < 4; c++) {
            const unsigned char* Vb = Vp + (size_t)eblk * 4096 + (c * 2) * 512 + lane32;
            vb0[c] = *(const long long*)(Vb);
            vb1[c] = *(const long long*)(Vb + 512);
        }
        long long pa0 = *(const long long*)&P[l16][n0 + g * 8];
        long long pa1 = *(const long long*)&P[l16][n0 + 32 + g * 8];
        #pragma unroll
        for (int c = 0; c < 4; c++) {
            accp[c] = mfma8(pa0, vb0[c], accp[c]);
            accp[c] = mfma8(pa1, vb1[c], accp[c]);
        }
        #pragma unroll
        for (int r4 = 0; r4 < 4; r4++) {
            int row = r4 * 4 + g;
            unsigned u = *(const unsigned*)&P[row][n0 + l16 * 4];
            float iv = inv_lds[row];
            f32x4 o;
            o[0] = __builtin_amdgcn_cvt_f32_fp8((int)u, 0) * iv;
            o[1] = __builtin_amdgcn_cvt_f32_fp8((int)u, 1) * iv;
            o[2] = __builtin_amdgcn_cvt_f32_fp8((int)u, 2) * iv;
            o[3] = __builtin_amdgcn_cvt_f32_fp8((int)u, 3) * iv;
            *(f32x4*)&a_out[((size_t)bh * NE + m0 + row) * NE + n0 + l16 * 4] = o;
        }
    }

    // ---------------- combine PV partials across 8 waves (alias P) ------------
    __syncthreads();
    float (*pvcomb)[16][64] = (float (*)[16][64])&P[0][0];  // 28.7 KB <= 33 KB
    if (ph > 0) {
        #pragma unroll
        for (int c = 0; c < 4; c++)
            #pragma unroll
            for (int r = 0; r < 4; r++)
                pvcomb[ph - 1][g * 4 + r][c * 16 + l16] = accp[c][r];
    }
    __syncthreads();
    if (ph == 0) {
        #pragma unroll
        for (int c = 0; c < 4; c++) {
            #pragma unroll
            for (int r = 0; r < 4; r++) {
                float v = accp[c][r];
                #pragma unroll
                for (int w = 0; w < 7; w++) v += pvcomb[w][g * 4 + r][c * 16 + l16];
                v *= inv_lds[g * 4 + r];
                oatb[(size_t)(b * NE + m0 + g * 4 + r) * 256 + h * 64 + c * 16 + l16] = f2b(v);
            }
        }
    }
}

// ---------------- fc GEMM + residual from x + transposed store ----------------
__global__ __launch_bounds__(256) void k_gemm_fc(const short* __restrict__ A,
        const short* __restrict__ W, const float* __restrict__ x,
        float* __restrict__ xout) {
    int t = threadIdx.x;
    int wv_ = t >> 6, lane = t & 63;
    int l16 = lane & 15, g = lane >> 4, lk = g * 8;
    int m0 = blockIdx.x * 64, n0 = blockIdx.y * 64;
    int mw = m0 + wv_ * 16;
    const short* Ab = A + (size_t)(mw + l16) * 256 + lk;
    const short* Wb = W + (size_t)(n0 + l16) * 256 + lk;
    f32x4 acc[4];
    f32x4 z4 = {0.f, 0.f, 0.f, 0.f};
    #pragma unroll
    for (int c = 0; c < 4; c++) acc[c] = z4;
    #pragma unroll
    for (int kk = 0; kk < 8; kk++) {
        bf16x8 av = *(const bf16x8*)(Ab + kk * 32);
        #pragma unroll
        for (int c = 0; c < 4; c++) {
            bf16x8 bv = *(const bf16x8*)(Wb + (size_t)c * 16 * 256 + kk * 32);
            acc[c] = mfma16(av, bv, acc[c]);
        }
    }
    __shared__ float tl[64][68];
    #pragma unroll
    for (int c = 0; c < 4; c++)
        #pragma unroll
        for (int r = 0; r < 4; r++)
            tl[c * 16 + l16][wv_ * 16 + g * 4 + r] = acc[c][r];
    __syncthreads();
    int b = m0 >> 11, e0 = m0 & (NE - 1);
    int dl = t >> 2, ec = (t & 3) * 16;
    #pragma unroll
    for (int i = 0; i < 4; i++) {
        size_t idx = ((size_t)b * ND + n0 + dl) * NE + e0 + ec + i * 4;
        f32x4 xv = *(const f32x4*)&x[idx];
        f32x4 v = *(f32x4*)&tl[dl][ec + i * 4];
        v[0] += xv[0]; v[1] += xv[1]; v[2] += xv[2]; v[3] += xv[3];
        *(f32x4*)&xout[idx] = v;
    }
}

extern "C" void kernel_launch(void* const* d_in, const int* in_sizes, int n_in,
                              void* d_out, int out_size, void* d_ws, size_t ws_size,
                              hipStream_t stream) {
    const float* x    = (const float*)d_in[0];
    const int*   dist = (const int*)d_in[1];
    const float* w_qs = (const float*)d_in[2];
    const float* w_ks = (const float*)d_in[3];
    const float* w_vs = (const float*)d_in[4];
    const float* w_fc = (const float*)d_in[5];
    const float* w_rpr= (const float*)d_in[6];
    const float* ln_g = (const float*)d_in[7];
    const float* ln_b = (const float*)d_in[8];

    char* ws = (char*)d_ws;
    short* sbf  = (short*)(ws);                            // 2 MB
    short* qnb  = (short*)(ws + (2u  << 20));              // 2 MB
    unsigned char* qf8  = (unsigned char*)(ws + (4u << 20));   // 1 MB
    unsigned char* kp8  = (unsigned char*)(ws + (5u << 20));   // 1 MB
    unsigned char* vp8  = (unsigned char*)(ws + (6u << 20));   // 1 MB
    short* oatb = (short*)(ws + (7u  << 20));              // 2 MB
    uint4* qdrT8 = (uint4*)(ws + (9u << 20));              // 256 KB
    unsigned char* d8p = (unsigned char*)(ws + (10u << 20)); // 8.4 MB
    short* wqsb = (short*)(ws + (19u << 20));
    short* wksb = (short*)(ws + (19u << 20) + 131072);
    short* wvsb = (short*)(ws + (19u << 20) + 262144);
    short* wfcb = (short*)(ws + (19u << 20) + 393216);

    float* xout  = (float*)d_out;
    float* a_out = xout + (size_t)NB * ND * NE;

    k_front<<<dim3(448), dim3(512), 0, stream>>>(dist, d8p,
            w_qs, w_ks, w_vs, w_fc, wqsb, wksb, wvsb, wfcb,
            x, ln_g, ln_b, sbf, qnb);
    k_gemm_qkv<<<dim3(64, 4, 3), dim3(256), 0, stream>>>(qnb, sbf, wqsb, wksb, wvsb,
                                                         w_rpr, qf8, kp8, vp8, qdrT8);
    k_attn<<<dim3(NE / 16, NB * NH), dim3(512), 0, stream>>>(qf8, kp8, d8p, qdrT8,
                                                             vp8, a_out, oatb);
    k_gemm_fc<<<dim3(64, 4), dim3(256), 0, stream>>>(oatb, wfcb, x, xout);
}